// Round 13
// baseline (76.140 us; speedup 1.0000x reference)
//
#include <hip/hip_runtime.h>
#include <math.h>

#define NNODES   8192
#define NODE_NUM 256
#define MAX_DEG  16
#define N_FEAT   128
#define N_HID    256
#define N_CLASS  64

#define AG_STRIDE 136    // agg row stride (shorts)
#define HB_STRIDE 264    // h row stride (shorts)

typedef __attribute__((ext_vector_type(8))) short bf16x8;
typedef __attribute__((ext_vector_type(4))) float f32x4;

// f32 -> bf16 round-to-nearest-even
static __device__ __forceinline__ short f2b(float f) {
    unsigned u = __float_as_uint(f);
    unsigned r = (u + 0x7fffu + ((u >> 16) & 1u)) >> 16;
    return (short)r;
}
static __device__ __forceinline__ float b2f(short s) {
    return __uint_as_float(((unsigned)(unsigned short)s) << 16);
}

// dedup/validity mask from raw neighbor ids (bit k = valid & first occurrence)
static __device__ __forceinline__ unsigned dedup_mask(const int* ids) {
    unsigned m = 0;
#pragma unroll
    for (int k = 0; k < MAX_DEG; ++k) {
        bool skip = (ids[k] == -1);
#pragma unroll
        for (int q = 0; q < k; ++q) skip = skip || (ids[q] == ids[k]);
        if (!skip) m |= 1u << k;
    }
    return m;
}

// ---------------------------------------------------------------------------
// K1: 256 WGs x 512 thr; each WG owns 32 rows. Self-contained (no prep):
//   - weight fragments loaded directly from W1/W2 (scalar f2b; L1-broadcast,
//     issued first so latency hides under the gather)
//   - dedup mask inline (pure VALU); BRANCHLESS gather-aggregate (R11-proven)
//   - MFMA GEMM1+relu -> hb LDS ; MFMA GEMM2 -> t2 bf16 (ws)
// MFMA 16x16x32 bf16 layouts (R3..R11-verified):
//   A: lane l holds A[row=l&15][k=8*(l>>4)+j]
//   B: lane l holds B[k=8*(l>>4)+j][col=l&15]
//   C: reg r -> row=(l>>4)*4+r, col=l&15
// ---------------------------------------------------------------------------
__global__ __launch_bounds__(512) void k_main(const float* __restrict__ x,
                                              const int* __restrict__ edge,
                                              const float* __restrict__ W1,
                                              const float* __restrict__ W2,
                                              short* __restrict__ t2b) {
    __shared__ short agg[32 * AG_STRIDE];   // 8704 B
    __shared__ short hb[32 * HB_STRIDE];    // 16896 B

    const int bid  = blockIdx.x;
    const int work = (bid & 7) * 32 + (bid >> 3);   // XCD-bijective swizzle
    const int row0 = work * 32;
    const int t    = threadIdx.x;
    const int w    = t >> 6, l = t & 63;
    const int l16  = l & 15, l4 = l >> 4;

    // ---- weight fragments: direct scalar loads (R6-proven ~2us marginal) ----
    bf16x8 w1f[4][4];
    {
        const int ntb = (w & 3) * 4;
#pragma unroll
        for (int n = 0; n < 4; ++n)
#pragma unroll
            for (int k4 = 0; k4 < 4; ++k4) {
                const int col = (ntb + n) * 16 + l16;
                const int kb  = k4 * 32 + l4 * 8;
                bf16x8 v;
#pragma unroll
                for (int j = 0; j < 8; ++j) v[j] = f2b(W1[(kb + j) * N_HID + col]);
                w1f[n][k4] = v;
            }
    }
    bf16x8 w2f[8];
    {
        const int col = (w & 3) * 16 + l16;
#pragma unroll
        for (int k8 = 0; k8 < 8; ++k8) {
            const int kb = k8 * 32 + l4 * 8;
            bf16x8 v;
#pragma unroll
            for (int j = 0; j < 8; ++j) v[j] = f2b(W2[(kb + j) * N_CLASS + col]);
            w2f[k8] = v;
        }
    }

    // ---- inline mask + branchless gather-aggregate from global x ----
    {
        const int r = t >> 4, c = t & 15;            // row 0..31, 8-feat chunk
        const int node = row0 + r;
        const int base = node & ~(NODE_NUM - 1);
        const int* e = edge + (size_t)node * MAX_DEG;
        int ids[MAX_DEG];
#pragma unroll
        for (int k = 0; k < MAX_DEG; ++k) ids[k] = e[k];
        const unsigned m = dedup_mask(ids);
        float a[8] = {0, 0, 0, 0, 0, 0, 0, 0};
#pragma unroll
        for (int k = 0; k < MAX_DEG; ++k) {
            const int id = ids[k] & (NODE_NUM - 1);  // -1 -> 255: in-bounds garbage
            const float sel = ((m >> k) & 1u) ? 1.0f : 0.0f;
            const float* rowp = x + (size_t)(base + id) * N_FEAT + c * 8;
            float4 v0 = *(const float4*)(rowp);
            float4 v1 = *(const float4*)(rowp + 4);
            a[0] = fmaf(sel, v0.x, a[0]); a[1] = fmaf(sel, v0.y, a[1]);
            a[2] = fmaf(sel, v0.z, a[2]); a[3] = fmaf(sel, v0.w, a[3]);
            a[4] = fmaf(sel, v1.x, a[4]); a[5] = fmaf(sel, v1.y, a[5]);
            a[6] = fmaf(sel, v1.z, a[6]); a[7] = fmaf(sel, v1.w, a[7]);
        }
        bf16x8 p;
#pragma unroll
        for (int j = 0; j < 8; ++j) p[j] = f2b(a[j]);
        *(bf16x8*)(&agg[r * AG_STRIDE + c * 8]) = p;
    }
    __syncthreads();

    // ---- GEMM1 + relu -> hb ----
    const int mt = w >> 2, ntc = w & 3;              // 2M x 4N wave tiles
    {
        bf16x8 af[4];
#pragma unroll
        for (int k4 = 0; k4 < 4; ++k4)
            af[k4] = *(const bf16x8*)(&agg[(mt * 16 + l16) * AG_STRIDE + k4 * 32 + l4 * 8]);
#pragma unroll
        for (int n = 0; n < 4; ++n) {
            f32x4 acc = {0.f, 0.f, 0.f, 0.f};
#pragma unroll
            for (int k4 = 0; k4 < 4; ++k4)
                acc = __builtin_amdgcn_mfma_f32_16x16x32_bf16(af[k4], w1f[n][k4], acc, 0, 0, 0);
#pragma unroll
            for (int r = 0; r < 4; ++r)
                hb[(mt * 16 + l4 * 4 + r) * HB_STRIDE + (ntc * 4 + n) * 16 + l16] =
                    f2b(fmaxf(acc[r], 0.f));
        }
    }
    __syncthreads();

    // ---- GEMM2 -> t2 (bf16, global ws) ----
    {
        f32x4 acc = {0.f, 0.f, 0.f, 0.f};
#pragma unroll
        for (int k8 = 0; k8 < 8; ++k8) {
            bf16x8 a = *(const bf16x8*)(&hb[(mt * 16 + l16) * HB_STRIDE + k8 * 32 + l4 * 8]);
            acc = __builtin_amdgcn_mfma_f32_16x16x32_bf16(a, w2f[k8], acc, 0, 0, 0);
        }
#pragma unroll
        for (int r = 0; r < 4; ++r)
            t2b[(size_t)(row0 + mt * 16 + l4 * 4 + r) * N_CLASS + ntc * 16 + l16] = f2b(acc[r]);
    }
}

// ---------------------------------------------------------------------------
// K2: out = log_softmax(A @ t2). 256 WGs x 256 thr; 32 nodes/WG;
// 8 lanes per node, 8 classes each; inline mask + branchless gather.
// ---------------------------------------------------------------------------
__global__ __launch_bounds__(256) void k_final(const short* __restrict__ t2b,
                                               const int* __restrict__ edge,
                                               float* __restrict__ out) {
    const int bid  = blockIdx.x;
    const int work = (bid & 7) * 32 + (bid >> 3);
    const int row0 = work * 32;
    const int t    = threadIdx.x;
    const int r = t >> 3, mm = t & 7;                // node 0..31, class octet
    const int node = row0 + r;
    const int base = node & ~(NODE_NUM - 1);
    const int* e = edge + (size_t)node * MAX_DEG;
    int ids[MAX_DEG];
#pragma unroll
    for (int k = 0; k < MAX_DEG; ++k) ids[k] = e[k];
    const unsigned m = dedup_mask(ids);

    float acc[8] = {0, 0, 0, 0, 0, 0, 0, 0};
#pragma unroll
    for (int k = 0; k < MAX_DEG; ++k) {
        const int id = ids[k] & (NODE_NUM - 1);
        const float sel = ((m >> k) & 1u) ? 1.0f : 0.0f;
        bf16x8 v = *(const bf16x8*)(t2b + (size_t)(base + id) * N_CLASS + mm * 8);
#pragma unroll
        for (int j = 0; j < 8; ++j) acc[j] = fmaf(sel, b2f(v[j]), acc[j]);
    }
    float mx = acc[0];
#pragma unroll
    for (int j = 1; j < 8; ++j) mx = fmaxf(mx, acc[j]);
#pragma unroll
    for (int o = 1; o < 8; o <<= 1) mx = fmaxf(mx, __shfl_xor(mx, o, 64));
    float s = 0.f;
#pragma unroll
    for (int j = 0; j < 8; ++j) s += expf(acc[j] - mx);
#pragma unroll
    for (int o = 1; o < 8; o <<= 1) s += __shfl_xor(s, o, 64);
    const float lse = mx + logf(s);

    float* op = out + (size_t)node * N_CLASS + mm * 8;
    float4 o0 = {acc[0] - lse, acc[1] - lse, acc[2] - lse, acc[3] - lse};
    float4 o1 = {acc[4] - lse, acc[5] - lse, acc[6] - lse, acc[7] - lse};
    *(float4*)(op)     = o0;
    *(float4*)(op + 4) = o1;
}

// ---------------------------------------------------------------------------
extern "C" void kernel_launch(void* const* d_in, const int* in_sizes, int n_in,
                              void* d_out, int out_size, void* d_ws, size_t ws_size,
                              hipStream_t stream) {
    const float* x    = (const float*)d_in[0];
    const int*   edge = (const int*)d_in[1];
    const float* W1   = (const float*)d_in[2];
    const float* W2   = (const float*)d_in[3];
    float* out = (float*)d_out;

    short* t2b = (short*)d_ws;                       // 1 MB

    k_main <<<NNODES / 32, 512, 0, stream>>>(x, edge, W1, W2, t2b);
    k_final<<<NNODES / 32, 256, 0, stream>>>(t2b, edge, out);
}

// Round 14
// 71.118 us; speedup vs baseline: 1.0706x; 1.0706x over previous
//
#include <hip/hip_runtime.h>
#include <math.h>

#define NNODES   8192
#define NODE_NUM 256
#define MAX_DEG  16
#define N_FEAT   128
#define N_HID    256
#define N_CLASS  64

#define AG_STRIDE 136    // agg row stride (shorts)
#define HB_STRIDE 264    // h row stride (shorts)

typedef __attribute__((ext_vector_type(8))) short bf16x8;
typedef __attribute__((ext_vector_type(4))) float f32x4;

// f32 -> bf16 round-to-nearest-even
static __device__ __forceinline__ short f2b(float f) {
    unsigned u = __float_as_uint(f);
    unsigned r = (u + 0x7fffu + ((u >> 16) & 1u)) >> 16;
    return (short)r;
}
static __device__ __forceinline__ float b2f(short s) {
    return __uint_as_float(((unsigned)(unsigned short)s) << 16);
}

// ---------------------------------------------------------------------------
// K0: one-shot prep. 256 WGs x 256 thr, one output element per thread.
//  g <  8192 : dedup/validity mask per node
//  g < 40960 : W1T pre-swizzled bf16 fragment store
//  g < 57344 : W2T likewise
// ---------------------------------------------------------------------------
__global__ __launch_bounds__(256) void k_prep(const int* __restrict__ edge,
                                              const float* __restrict__ W1,
                                              const float* __restrict__ W2,
                                              unsigned int* __restrict__ maskw,
                                              short* __restrict__ W1T,
                                              short* __restrict__ W2T) {
    const int g = blockIdx.x * 256 + threadIdx.x;
    if (g < 8192) {
        const int* e = edge + (size_t)g * MAX_DEG;
        int ids[MAX_DEG];
#pragma unroll
        for (int k = 0; k < MAX_DEG; ++k) ids[k] = e[k];
        unsigned m = 0;
#pragma unroll
        for (int k = 0; k < MAX_DEG; ++k) {
            bool skip = (ids[k] == -1);
#pragma unroll
            for (int q = 0; q < k; ++q) skip = skip || (ids[q] == ids[k]);
            if (!skip) m |= 1u << k;
        }
        maskw[g] = m;
    } else if (g < 40960) {
        const int o = g - 8192;
        const int j = o & 7, l = (o >> 3) & 63, k4 = (o >> 9) & 3, nt = (o >> 11) & 15;
        W1T[o] = f2b(W1[(k4 * 32 + (l >> 4) * 8 + j) * N_HID + nt * 16 + (l & 15)]);
    } else if (g < 57344) {
        const int o = g - 40960;
        const int j = o & 7, l = (o >> 3) & 63, k8 = (o >> 9) & 7, nt = (o >> 12) & 3;
        W2T[o] = f2b(W2[(k8 * 32 + (l >> 4) * 8 + j) * N_CLASS + nt * 16 + (l & 15)]);
    }
}

// ---------------------------------------------------------------------------
// K1: 256 WGs x 512 thr; each WG owns 32 rows.
//   - weight fragments: 24 coalesced b128 loads (pre-swizzled by K0)
//   - BRANCHLESS gather-aggregate: unconditional loads (id clamped in-bounds),
//     fmaf with 0/1 select from dedup mask -> all 32 loads pipeline
//   - MFMA GEMM1+relu -> hb LDS ; MFMA GEMM2 -> t2 bf16 (ws)
// MFMA 16x16x32 bf16 layouts (R3..R11-verified):
//   A: lane l holds A[row=l&15][k=8*(l>>4)+j]
//   B: lane l holds B[k=8*(l>>4)+j][col=l&15]
//   C: reg r -> row=(l>>4)*4+r, col=l&15
// ---------------------------------------------------------------------------
__global__ __launch_bounds__(512) void k_main(const float* __restrict__ x,
                                              const int* __restrict__ edge,
                                              const unsigned int* __restrict__ maskw,
                                              const short* __restrict__ W1T,
                                              const short* __restrict__ W2T,
                                              short* __restrict__ t2b) {
    __shared__ short agg[32 * AG_STRIDE];   // 8704 B
    __shared__ short hb[32 * HB_STRIDE];    // 16896 B

    const int bid  = blockIdx.x;
    const int work = (bid & 7) * 32 + (bid >> 3);   // XCD-bijective swizzle
    const int row0 = work * 32;
    const int t    = threadIdx.x;
    const int w    = t >> 6, l = t & 63;
    const int l16  = l & 15, l4 = l >> 4;

    // ---- weight fragments: coalesced vector loads, hidden under gather ----
    bf16x8 w1f[4][4];
    {
        const int ntb = (w & 3) * 4;
#pragma unroll
        for (int n = 0; n < 4; ++n)
#pragma unroll
            for (int k4 = 0; k4 < 4; ++k4)
                w1f[n][k4] = *(const bf16x8*)(W1T + ((size_t)((ntb + n) * 4 + k4) * 64 + l) * 8);
    }
    bf16x8 w2f[8];
    {
        const int nt = w & 3;
#pragma unroll
        for (int k8 = 0; k8 < 8; ++k8)
            w2f[k8] = *(const bf16x8*)(W2T + ((size_t)(nt * 8 + k8) * 64 + l) * 8);
    }

    // ---- branchless gather-aggregate from global x ----
    {
        const int r = t >> 4, c = t & 15;            // row 0..31, 8-feat chunk
        const int node = row0 + r;
        const int base = node & ~(NODE_NUM - 1);
        const int* e = edge + (size_t)node * MAX_DEG;
        const unsigned m = maskw[node];
        float a[8] = {0, 0, 0, 0, 0, 0, 0, 0};
#pragma unroll
        for (int k = 0; k < MAX_DEG; ++k) {
            const int id = e[k] & (NODE_NUM - 1);    // -1 -> 255: in-bounds garbage
            const float sel = ((m >> k) & 1u) ? 1.0f : 0.0f;
            const float* rowp = x + (size_t)(base + id) * N_FEAT + c * 8;
            float4 v0 = *(const float4*)(rowp);
            float4 v1 = *(const float4*)(rowp + 4);
            a[0] = fmaf(sel, v0.x, a[0]); a[1] = fmaf(sel, v0.y, a[1]);
            a[2] = fmaf(sel, v0.z, a[2]); a[3] = fmaf(sel, v0.w, a[3]);
            a[4] = fmaf(sel, v1.x, a[4]); a[5] = fmaf(sel, v1.y, a[5]);
            a[6] = fmaf(sel, v1.z, a[6]); a[7] = fmaf(sel, v1.w, a[7]);
        }
        bf16x8 p;
#pragma unroll
        for (int j = 0; j < 8; ++j) p[j] = f2b(a[j]);
        *(bf16x8*)(&agg[r * AG_STRIDE + c * 8]) = p;
    }
    __syncthreads();

    // ---- GEMM1 + relu -> hb ----
    const int mt = w >> 2, ntc = w & 3;              // 2M x 4N wave tiles
    {
        bf16x8 af[4];
#pragma unroll
        for (int k4 = 0; k4 < 4; ++k4)
            af[k4] = *(const bf16x8*)(&agg[(mt * 16 + l16) * AG_STRIDE + k4 * 32 + l4 * 8]);
#pragma unroll
        for (int n = 0; n < 4; ++n) {
            f32x4 acc = {0.f, 0.f, 0.f, 0.f};
#pragma unroll
            for (int k4 = 0; k4 < 4; ++k4)
                acc = __builtin_amdgcn_mfma_f32_16x16x32_bf16(af[k4], w1f[n][k4], acc, 0, 0, 0);
#pragma unroll
            for (int r = 0; r < 4; ++r)
                hb[(mt * 16 + l4 * 4 + r) * HB_STRIDE + (ntc * 4 + n) * 16 + l16] =
                    f2b(fmaxf(acc[r], 0.f));
        }
    }
    __syncthreads();

    // ---- GEMM2 -> t2 (bf16, global ws) ----
    {
        f32x4 acc = {0.f, 0.f, 0.f, 0.f};
#pragma unroll
        for (int k8 = 0; k8 < 8; ++k8) {
            bf16x8 a = *(const bf16x8*)(&hb[(mt * 16 + l16) * HB_STRIDE + k8 * 32 + l4 * 8]);
            acc = __builtin_amdgcn_mfma_f32_16x16x32_bf16(a, w2f[k8], acc, 0, 0, 0);
        }
#pragma unroll
        for (int r = 0; r < 4; ++r)
            t2b[(size_t)(row0 + mt * 16 + l4 * 4 + r) * N_CLASS + ntc * 16 + l16] = f2b(acc[r]);
    }
}

// ---------------------------------------------------------------------------
// K2: out = log_softmax(A @ t2). 256 WGs x 256 thr; 32 nodes/WG;
// 8 lanes per node, 8 classes each; branchless masked gather.
// ---------------------------------------------------------------------------
__global__ __launch_bounds__(256) void k_final(const short* __restrict__ t2b,
                                               const int* __restrict__ edge,
                                               const unsigned int* __restrict__ maskw,
                                               float* __restrict__ out) {
    const int bid  = blockIdx.x;
    const int work = (bid & 7) * 32 + (bid >> 3);
    const int row0 = work * 32;
    const int t    = threadIdx.x;
    const int r = t >> 3, mm = t & 7;                // node 0..31, class octet
    const int node = row0 + r;
    const int base = node & ~(NODE_NUM - 1);
    const int* e = edge + (size_t)node * MAX_DEG;
    const unsigned m = maskw[node];

    float acc[8] = {0, 0, 0, 0, 0, 0, 0, 0};
#pragma unroll
    for (int k = 0; k < MAX_DEG; ++k) {
        const int id = e[k] & (NODE_NUM - 1);
        const float sel = ((m >> k) & 1u) ? 1.0f : 0.0f;
        bf16x8 v = *(const bf16x8*)(t2b + (size_t)(base + id) * N_CLASS + mm * 8);
#pragma unroll
        for (int j = 0; j < 8; ++j) acc[j] = fmaf(sel, b2f(v[j]), acc[j]);
    }
    float mx = acc[0];
#pragma unroll
    for (int j = 1; j < 8; ++j) mx = fmaxf(mx, acc[j]);
#pragma unroll
    for (int o = 1; o < 8; o <<= 1) mx = fmaxf(mx, __shfl_xor(mx, o, 64));
    float s = 0.f;
#pragma unroll
    for (int j = 0; j < 8; ++j) s += expf(acc[j] - mx);
#pragma unroll
    for (int o = 1; o < 8; o <<= 1) s += __shfl_xor(s, o, 64);
    const float lse = mx + logf(s);

    float* op = out + (size_t)node * N_CLASS + mm * 8;
    float4 o0 = {acc[0] - lse, acc[1] - lse, acc[2] - lse, acc[3] - lse};
    float4 o1 = {acc[4] - lse, acc[5] - lse, acc[6] - lse, acc[7] - lse};
    *(float4*)(op)     = o0;
    *(float4*)(op + 4) = o1;
}

// ---------------------------------------------------------------------------
extern "C" void kernel_launch(void* const* d_in, const int* in_sizes, int n_in,
                              void* d_out, int out_size, void* d_ws, size_t ws_size,
                              hipStream_t stream) {
    const float* x    = (const float*)d_in[0];
    const int*   edge = (const int*)d_in[1];
    const float* W1   = (const float*)d_in[2];
    const float* W2   = (const float*)d_in[3];
    float* out = (float*)d_out;

    char* ws = (char*)d_ws;
    unsigned int* maskw = (unsigned int*)ws;             // 32 KB
    short*        W1T   = (short*)(ws + (32 << 10));     // 64 KB
    short*        W2T   = (short*)(ws + (96 << 10));     // 32 KB
    short*        t2b   = (short*)(ws + (128 << 10));    // 1 MB

    k_prep <<<256,         256, 0, stream>>>(edge, W1, W2, maskw, W1T, W2T);
    k_main <<<NNODES / 32, 512, 0, stream>>>(x, edge, maskw, W1T, W2T, t2b);
    k_final<<<NNODES / 32, 256, 0, stream>>>(t2b, edge, maskw, out);
}